// Round 7
// baseline (312.616 us; speedup 1.0000x reference)
//
#include <hip/hip_runtime.h>
#include <hip/hip_bf16.h>

// ---------------------------------------------------------------------------
// MultiheadAttention (B=4, S=8192, E=1024, H=16, D=64) — bf16 MFMA.
// R7: raise blocks/CU on the two big GEMMs (qkv: 32-row tiles, 1024 blocks,
// 3/CU; gemm_o: 32x64 tiles, 1024 blocks, 4/CU). Staging mechanics unchanged
// from R6 (global_load_lds dbuf, one barrier/step). attn/vtrans/convw
// unchanged.
//
//   qkv = x @ [Wq*0.125 | Wk | Wv]^T + [bq*0.125 | bk | bv]   (bf16, 32768x192)
//   Qh[b,h,i,d] = qkv[b*8192 + i*16 + h][d]      (S' = 512)
//   fused: ctx[b*512+i][h*64+d] = softmax(Qh Kh^T) @ Vh   (no score buffer)
//   out = ctx @ Wo^T + bo (fp32)
//
// MFMA 16x16x32 bf16 layouts (m89/m91-verified):
//   A frag: lane q*16+r holds A[m=r][k=q*8+j]
//   B frag: lane q*16+r holds B[n=r][k=q*8+j]
//   C/D   : lane q*16+r holds D[row=q*4+e][col=r]
// ---------------------------------------------------------------------------

typedef unsigned short u16;
typedef __attribute__((ext_vector_type(8))) short short8;
typedef __attribute__((ext_vector_type(4))) float f32x4;

__device__ inline u16 f2bf(float f) {
    union { float f; unsigned u; } v; v.f = f;
    unsigned u = v.u;
    return (u16)((u + 0x7fffu + ((u >> 16) & 1u)) >> 16);  // RNE
}
__device__ inline unsigned pack_bf2(float a, float b) {
    union { __hip_bfloat162 h; unsigned u; } v;
    v.h = __float22bfloat162_rn(float2{a, b});
    return v.u;
}
// Async global->LDS, 16 B per lane. LDS dest = wave-uniform base + lane*16.
__device__ __forceinline__ void gld16(void* lds, const void* gptr) {
    __builtin_amdgcn_global_load_lds(
        (const __attribute__((address_space(1))) unsigned int*)gptr,
        (__attribute__((address_space(3))) unsigned int*)lds,
        16, 0, 0);
}

// ---------------------------------------------------------------------------
// Weight/bias conversion.
// ---------------------------------------------------------------------------
__global__ __launch_bounds__(256) void convw(
    const float* __restrict__ Wq, const float* __restrict__ bq,
    const float* __restrict__ Wk, const float* __restrict__ bk,
    const float* __restrict__ Wv, const float* __restrict__ bv,
    const float* __restrict__ Wo,
    u16* __restrict__ Wqkv, float* __restrict__ qkvb, u16* __restrict__ Wob)
{
    const int idx = blockIdx.x * 256 + threadIdx.x;   // 0 .. 1048575
    Wob[idx] = f2bf(Wo[idx]);
    if (idx < 196608) {
        const int row = idx >> 10, k = idx & 1023;
        float v = (row < 64)  ? Wq[row * 1024 + k] * 0.125f
                : (row < 128) ? Wk[(row - 64) * 1024 + k]
                              : Wv[(row - 128) * 1024 + k];
        Wqkv[idx] = f2bf(v);
    }
    if (idx < 192) {
        qkvb[idx] = (idx < 64) ? bq[idx] * 0.125f
                  : (idx < 128) ? bk[idx - 64] : bv[idx - 128];
    }
}

// ---------------------------------------------------------------------------
// Fused QKV projection: qkv[32768][192] = bf16(X fp32) @ Wqkv^T + b.
// 1024 blocks x 4 waves; 32-row tile. Wave (wid): m-tile = wid>>1,
// n-half = (wid&1)*6 n-tiles -> 16 rows x 96 cols, acc = 6 f32x4.
// BK=64: B staged via global_load_lds (24 sections of 1 KB; 6 per wave),
// double-buffered, one barrier per step. A frags per-lane direct fp32 +
// in-reg pack, register-prefetched. LDS 48 KB -> 3 blocks/CU.
// ---------------------------------------------------------------------------
__global__ __launch_bounds__(256) void qkv_gemm(
    const float* __restrict__ X, const u16* __restrict__ W,
    const float* __restrict__ bias, u16* __restrict__ Out)
{
    __shared__ short8 Bs[2][1536];   // [p*64 + lane], p = kk2*12 + nt

    const int tid = threadIdx.x;
    const int lane = tid & 63, wid = tid >> 6;
    const int q = lane >> 4, r = lane & 15;
    const long m0 = (long)blockIdx.x * 32;
    const int mt = wid >> 1;          // wave's m-tile (0/1)
    const int nh = (wid & 1) * 6;     // wave's n-tile base (0/6)

    // B staging pointers: this wave covers p = wid*6 .. wid*6+5
    const u16* wp[6];
    #pragma unroll
    for (int i = 0; i < 6; ++i) {
        const int p = wid * 6 + i, kk2 = p / 12, nt = p % 12;
        wp[i] = W + (long)(nt * 16 + r) * 1024 + kk2 * 32 + q * 8;
    }

    const float* px = X + (m0 + mt * 16 + r) * 1024 + q * 8;

    f32x4 acc[6] = {};

    // prologue: stage step 0 into buf 0; load step-0 A regs
    #pragma unroll
    for (int i = 0; i < 6; ++i)
        gld16(&Bs[0][(wid * 6 + i) * 64], wp[i]);
    float4 a[4];
    a[0] = *(const float4*)(px);
    a[1] = *(const float4*)(px + 4);
    a[2] = *(const float4*)(px + 32);
    a[3] = *(const float4*)(px + 36);
    __syncthreads();

    for (int k0 = 0; k0 < 1024; k0 += 64) {
        const int buf = (k0 >> 6) & 1;
        float4 an[4] = {};
        if (k0 + 64 < 1024) {
            #pragma unroll
            for (int i = 0; i < 6; ++i)
                gld16(&Bs[buf ^ 1][(wid * 6 + i) * 64], wp[i] + k0 + 64);
            an[0] = *(const float4*)(px + k0 + 64);
            an[1] = *(const float4*)(px + k0 + 68);
            an[2] = *(const float4*)(px + k0 + 96);
            an[3] = *(const float4*)(px + k0 + 100);
        }
        #pragma unroll
        for (int kk2 = 0; kk2 < 2; ++kk2) {
            union { short8 s; unsigned u[4]; } af;
            af.u[0] = pack_bf2(a[kk2 * 2].x, a[kk2 * 2].y);
            af.u[1] = pack_bf2(a[kk2 * 2].z, a[kk2 * 2].w);
            af.u[2] = pack_bf2(a[kk2 * 2 + 1].x, a[kk2 * 2 + 1].y);
            af.u[3] = pack_bf2(a[kk2 * 2 + 1].z, a[kk2 * 2 + 1].w);
            #pragma unroll
            for (int j = 0; j < 6; ++j)
                acc[j] = __builtin_amdgcn_mfma_f32_16x16x32_bf16(
                    af.s, Bs[buf][(kk2 * 12 + nh + j) * 64 + lane],
                    acc[j], 0, 0, 0);
        }
        __syncthreads();
        #pragma unroll
        for (int i = 0; i < 4; ++i) a[i] = an[i];
    }

    #pragma unroll
    for (int j = 0; j < 6; ++j) {
        const int col = (nh + j) * 16 + r;
        const float badd = bias[col];
        #pragma unroll
        for (int e = 0; e < 4; ++e) {
            const long row = m0 + mt * 16 + q * 4 + e;
            Out[row * 192 + col] = f2bf(acc[j][e] + badd);
        }
    }
}

// ---------------------------------------------------------------------------
// V transpose: Vt[bh*64 + d][i] <- qkv[b*8192 + i*16 + h][128 + d]
// ---------------------------------------------------------------------------
__global__ __launch_bounds__(256) void vtrans(
    const u16* __restrict__ qkv, u16* __restrict__ Vt)
{
    __shared__ u16 T[64][68];
    const int bh = blockIdx.x, b = bh >> 4, h = bh & 15;
    const int i0 = blockIdx.y * 64;
    const int tid = threadIdx.x;

    #pragma unroll
    for (int it = 0; it < 2; ++it) {
        const int c = tid + 256 * it;
        const int il = c >> 3, d8 = (c & 7) * 8;
        short8 v = *(const short8*)(qkv +
            ((long)b * 8192 + (long)(i0 + il) * 16 + h) * 192 + 128 + d8);
        #pragma unroll
        for (int j = 0; j < 8; ++j) T[d8 + j][il] = (u16)v[j];
    }
    __syncthreads();
    #pragma unroll
    for (int it = 0; it < 2; ++it) {
        const int c = tid + 256 * it;
        const int dl = c >> 3, i8 = (c & 7) * 8;
        short8 o;
        #pragma unroll
        for (int j = 0; j < 8; ++j) o[j] = (short)T[dl][i8 + j];
        *(short8*)(Vt + ((long)bh * 64 + dl) * 512 + i0 + i8) = o;
    }
}

// ---------------------------------------------------------------------------
// Fused flash attention, S^T formulation (unchanged from R6).
// ---------------------------------------------------------------------------
__global__ __launch_bounds__(256) void attn_flash(
    const u16* __restrict__ qkv, const u16* __restrict__ Vt,
    u16* __restrict__ ctx)
{
    __shared__ short8 Ks[2][512];      // [f*256 + ct*64 + q*16 + r]
    __shared__ short8 Vs[2][512];      // [f*256 + nt*64 + q*16 + r]
    __shared__ u16 Plds[4][16 * 72];   // wave-private P[query][key]

    const int tid = threadIdx.x, lane = tid & 63, wid = tid >> 6;
    const int q = lane >> 4, r = lane & 15;
    const int qt = blockIdx.x;         // 0..7
    const int bh = blockIdx.y;         // 0..63
    const int b = bh >> 4, h = bh & 15;
    const long qrowbase = (long)b * 8192 + h;

    // Q B-fragments: lane(q,r) needs Q[query=r][d=q*8+j] (2 d-halves)
    short8 Qf0, Qf1;
    {
        const int i = qt * 64 + wid * 16 + r;
        const u16* p = qkv + (qrowbase + (long)i * 16) * 192 + q * 8;
        Qf0 = *(const short8*)(p);
        Qf1 = *(const short8*)(p + 32);
    }

    const u16* kbase = qkv + (qrowbase + (long)(wid * 16 + r) * 16) * 192
                           + 64 + q * 8;                 // + key*3072 + f*32
    const u16* vbase = Vt + ((long)bh * 64 + wid * 16 + r) * 512 + q * 8;

    gld16(&Ks[0][wid * 64],       kbase);
    gld16(&Ks[0][256 + wid * 64], kbase + 32);
    gld16(&Vs[0][wid * 64],       vbase);
    gld16(&Vs[0][256 + wid * 64], vbase + 32);
    __syncthreads();

    f32x4 O[4] = {};
    float mrun = -1e30f, lrun = 0.f;   // per-lane scalars (query = r)
    u16* Pw = &Plds[wid][0];

    for (int c = 0; c < 8; ++c) {
        const int j0 = c * 64, buf = c & 1;
        if (c < 7) {
            const u16* kp = kbase + (long)(j0 + 64) * 3072;
            const u16* vp = vbase + j0 + 64;
            gld16(&Ks[buf ^ 1][wid * 64],       kp);
            gld16(&Ks[buf ^ 1][256 + wid * 64], kp + 32);
            gld16(&Vs[buf ^ 1][wid * 64],       vp);
            gld16(&Vs[buf ^ 1][256 + wid * 64], vp + 32);
        }
        // ---- S^T chunk: lane holds S^T[key=ct*16+q*4+e][query r] ----
        f32x4 S[4];
        #pragma unroll
        for (int ct = 0; ct < 4; ++ct) {
            f32x4 s = {};
            s = __builtin_amdgcn_mfma_f32_16x16x32_bf16(
                Ks[buf][ct * 64 + lane], Qf0, s, 0, 0, 0);
            s = __builtin_amdgcn_mfma_f32_16x16x32_bf16(
                Ks[buf][256 + ct * 64 + lane], Qf1, s, 0, 0, 0);
            S[ct] = s;
        }
        // ---- online softmax (per query r): in-lane 16 + 2 shuffles ----
        float mc = -1e30f;
        #pragma unroll
        for (int ct = 0; ct < 4; ++ct)
            mc = fmaxf(mc, fmaxf(fmaxf(S[ct][0], S[ct][1]),
                                 fmaxf(S[ct][2], S[ct][3])));
        mc = fmaxf(mc, __shfl_xor(mc, 16, 64));
        mc = fmaxf(mc, __shfl_xor(mc, 32, 64));
        const float mnew = fmaxf(mrun, mc);
        const float alpha = __expf(mrun - mnew);
        mrun = mnew;
        float se = 0.f;
        #pragma unroll
        for (int ct = 0; ct < 4; ++ct)
            #pragma unroll
            for (int e = 0; e < 4; ++e) {
                const float pv = __expf(S[ct][e] - mnew);
                S[ct][e] = pv; se += pv;
            }
        se += __shfl_xor(se, 16, 64);
        se += __shfl_xor(se, 32, 64);
        lrun = lrun * alpha + se;
        #pragma unroll
        for (int nt = 0; nt < 4; ++nt)
            #pragma unroll
            for (int e = 0; e < 4; ++e) O[nt][e] *= alpha;
        // ---- P^T -> LDS as P[query][key], packed b64 writes ----
        #pragma unroll
        for (int ct = 0; ct < 4; ++ct) {
            uint2 d;
            d.x = pack_bf2(S[ct][0], S[ct][1]);
            d.y = pack_bf2(S[ct][2], S[ct][3]);
            *(uint2*)(Pw + r * 72 + ct * 16 + q * 4) = d;
        }
        short8 Pf0 = *(const short8*)(Pw + r * 72 + q * 8);
        short8 Pf1 = *(const short8*)(Pw + r * 72 + 32 + q * 8);
        // ---- O^T += MFMA(A=V^T, B=P) ----
        #pragma unroll
        for (int nt = 0; nt < 4; ++nt) {
            O[nt] = __builtin_amdgcn_mfma_f32_16x16x32_bf16(
                Vs[buf][nt * 64 + lane], Pf0, O[nt], 0, 0, 0);
            O[nt] = __builtin_amdgcn_mfma_f32_16x16x32_bf16(
                Vs[buf][256 + nt * 64 + lane], Pf1, O[nt], 0, 0, 0);
        }
        __syncthreads();
    }

    // ---- epilogue: normalize, write ctx[b*512+i][h*64+d], 8B stores ----
    const float inv = 1.0f / lrun;
    const long i = qt * 64 + wid * 16 + r;
    u16* po = ctx + ((long)b * 512 + i) * 1024 + h * 64;
    #pragma unroll
    for (int nt = 0; nt < 4; ++nt) {
        uint2 d;
        d.x = pack_bf2(O[nt][0] * inv, O[nt][1] * inv);
        d.y = pack_bf2(O[nt][2] * inv, O[nt][3] * inv);
        *(uint2*)(po + nt * 16 + q * 4) = d;
    }
}

// ---------------------------------------------------------------------------
// Output projection: out[2048][1024] fp32 = ctx @ Wob^T + bo.
// 32x64 tile, grid (64,16)=1024 blocks -> 4 blocks/CU (LDS 24 KB).
// Wave (wid): m-tile = wid>>1, n-pair = (wid&1)*2 -> 16m x 32n, acc 2 f32x4.
// BK=64 dbuf via global_load_lds; 12 sections (4 A + 8 B), 3 per wave;
// one barrier per step.
// ---------------------------------------------------------------------------
__global__ __launch_bounds__(256) void gemm_o(
    const u16* __restrict__ A, const u16* __restrict__ B,
    const float* __restrict__ bias, float* __restrict__ C)
{
    __shared__ short8 Ls[2][768];   // A: (f*2+m2)*64 ; B: 256 + (f*4+nt)*64

    const int tid = threadIdx.x;
    const int lane = tid & 63, wid = tid >> 6;
    const int q = lane >> 4, r = lane & 15;
    const long m0 = (long)blockIdx.x * 32, n0 = (long)blockIdx.y * 64;
    const int mt = wid >> 1, wn = wid & 1;

    // staging: this wave covers sections s = wid*3 .. wid*3+2
    const u16* sp[3];
    int slot[3];
    #pragma unroll
    for (int i = 0; i < 3; ++i) {
        const int s = wid * 3 + i;
        if (s < 4) {
            const int f = s >> 1, m2 = s & 1;
            sp[i] = A + (m0 + m2 * 16 + r) * 1024 + f * 32 + q * 8;
            slot[i] = (f * 2 + m2) * 64;
        } else {
            const int t = s - 4, f = t >> 2, nt = t & 3;
            sp[i] = B + (n0 + nt * 16 + r) * 1024 + f * 32 + q * 8;
            slot[i] = 256 + (f * 4 + nt) * 64;
        }
    }

    #pragma unroll
    for (int i = 0; i < 3; ++i)
        gld16(&Ls[0][slot[i]], sp[i]);
    __syncthreads();

    f32x4 acc[2] = {};

    for (int k0 = 0; k0 < 1024; k0 += 64) {
        const int buf = (k0 >> 6) & 1;
        if (k0 + 64 < 1024) {
            #pragma unroll
            for (int i = 0; i < 3; ++i)
                gld16(&Ls[buf ^ 1][slot[i]], sp[i] + k0 + 64);
        }
        #pragma unroll
        for (int f = 0; f < 2; ++f) {
            short8 af  = Ls[buf][(f * 2 + mt) * 64 + lane];
            short8 bf0 = Ls[buf][256 + (f * 4 + wn * 2 + 0) * 64 + lane];
            short8 bf1 = Ls[buf][256 + (f * 4 + wn * 2 + 1) * 64 + lane];
            acc[0] = __builtin_amdgcn_mfma_f32_16x16x32_bf16(af, bf0, acc[0], 0, 0, 0);
            acc[1] = __builtin_amdgcn_mfma_f32_16x16x32_bf16(af, bf1, acc[1], 0, 0, 0);
        }
        __syncthreads();
    }

    #pragma unroll
    for (int j = 0; j < 2; ++j) {
        const long col = n0 + (wn * 2 + j) * 16 + r;
        const float badd = bias[col];
        #pragma unroll
        for (int e = 0; e < 4; ++e) {
            const long row = m0 + mt * 16 + q * 4 + e;
            C[row * 1024 + col] = acc[j][e] + badd;
        }
    }
}

// ---------------------------------------------------------------------------
extern "C" void kernel_launch(void* const* d_in, const int* in_sizes, int n_in,
                              void* d_out, int out_size, void* d_ws, size_t ws_size,
                              hipStream_t stream)
{
    const float* x  = (const float*)d_in[0];
    const float* Wq = (const float*)d_in[1];
    const float* bq = (const float*)d_in[2];
    const float* Wk = (const float*)d_in[3];
    const float* bk = (const float*)d_in[4];
    const float* Wv = (const float*)d_in[5];
    const float* bv = (const float*)d_in[6];
    const float* Wo = (const float*)d_in[7];
    const float* bo = (const float*)d_in[8];
    float* out = (float*)d_out;
    char* ws = (char*)d_ws;

    u16*   qkv  = (u16*)(ws);                   // 32768*192*2   = 12,582,912
    u16*   Vt   = (u16*)(ws + 12582912);        // 64*64*512*2   =  4,194,304
    u16*   Wqkv = (u16*)(ws + 16777216);        // 192*1024*2    =    393,216
    u16*   Wob  = (u16*)(ws + 17170432);        // 1024*1024*2   =  2,097,152
    float* qkvb = (float*)(ws + 19267584);      // 192*4
    u16*   ctx  = (u16*)(ws + 19268352);        // 2048*1024*2   =  4,194,304

    convw<<<4096, 256, 0, stream>>>(Wq, bq, Wk, bk, Wv, bv, Wo, Wqkv, qkvb, Wob);
    qkv_gemm<<<1024, 256, 0, stream>>>(x, Wqkv, qkvb, qkv);
    vtrans<<<dim3(64, 8), 256, 0, stream>>>(qkv, Vt);
    attn_flash<<<dim3(8, 64), 256, 0, stream>>>(qkv, Vt, ctx);
    gemm_o<<<dim3(64, 16), 256, 0, stream>>>(ctx, Wob, bo, out);
}

// Round 8
// 265.009 us; speedup vs baseline: 1.1796x; 1.1796x over previous
//
#include <hip/hip_runtime.h>
#include <hip/hip_bf16.h>

// ---------------------------------------------------------------------------
// MultiheadAttention (B=4, S=8192, E=1024, H=16, D=64) — bf16 MFMA.
// R8: R6 anchor (best measured, 263.8 us total) with ONE change: qkv_gemm
// uses 512-thread blocks covering 128 rows (8 waves x 16 rows), sharing one
// 48 KB B-staging dbuf -> staging instrs/thread/step halve (6->3 gld16),
// W L2 traffic halves. Everything else byte-identical to R6.
//
//   qkv = x @ [Wq*0.125 | Wk | Wv]^T + [bq*0.125 | bk | bv]   (bf16, 32768x192)
//   Qh[b,h,i,d] = qkv[b*8192 + i*16 + h][d]      (S' = 512)
//   fused: ctx[b*512+i][h*64+d] = softmax(Qh Kh^T) @ Vh   (no score buffer)
//   out = ctx @ Wo^T + bo (fp32)
//
// MFMA 16x16x32 bf16 layouts (m89/m91-verified):
//   A frag: lane q*16+r holds A[m=r][k=q*8+j]
//   B frag: lane q*16+r holds B[n=r][k=q*8+j]
//   C/D   : lane q*16+r holds D[row=q*4+e][col=r]
// ---------------------------------------------------------------------------

typedef unsigned short u16;
typedef __attribute__((ext_vector_type(8))) short short8;
typedef __attribute__((ext_vector_type(4))) float f32x4;

__device__ inline u16 f2bf(float f) {
    union { float f; unsigned u; } v; v.f = f;
    unsigned u = v.u;
    return (u16)((u + 0x7fffu + ((u >> 16) & 1u)) >> 16);  // RNE
}
__device__ inline unsigned pack_bf2(float a, float b) {
    union { __hip_bfloat162 h; unsigned u; } v;
    v.h = __float22bfloat162_rn(float2{a, b});
    return v.u;
}
// Async global->LDS, 16 B per lane. LDS dest = wave-uniform base + lane*16.
__device__ __forceinline__ void gld16(void* lds, const void* gptr) {
    __builtin_amdgcn_global_load_lds(
        (const __attribute__((address_space(1))) unsigned int*)gptr,
        (__attribute__((address_space(3))) unsigned int*)lds,
        16, 0, 0);
}

// ---------------------------------------------------------------------------
// Weight/bias conversion.
// ---------------------------------------------------------------------------
__global__ __launch_bounds__(256) void convw(
    const float* __restrict__ Wq, const float* __restrict__ bq,
    const float* __restrict__ Wk, const float* __restrict__ bk,
    const float* __restrict__ Wv, const float* __restrict__ bv,
    const float* __restrict__ Wo,
    u16* __restrict__ Wqkv, float* __restrict__ qkvb, u16* __restrict__ Wob)
{
    const int idx = blockIdx.x * 256 + threadIdx.x;   // 0 .. 1048575
    Wob[idx] = f2bf(Wo[idx]);
    if (idx < 196608) {
        const int row = idx >> 10, k = idx & 1023;
        float v = (row < 64)  ? Wq[row * 1024 + k] * 0.125f
                : (row < 128) ? Wk[(row - 64) * 1024 + k]
                              : Wv[(row - 128) * 1024 + k];
        Wqkv[idx] = f2bf(v);
    }
    if (idx < 192) {
        qkvb[idx] = (idx < 64) ? bq[idx] * 0.125f
                  : (idx < 128) ? bk[idx - 64] : bv[idx - 128];
    }
}

// ---------------------------------------------------------------------------
// Fused QKV projection: qkv[32768][192] = bf16(X fp32) @ Wqkv^T + b.
// 256 blocks x 8 waves (512 threads); block = 128 rows, wave w owns m-tile w
// (16 rows) x 192 cols (12 n-tiles, acc 12 f32x4). BK=64: B staged via
// global_load_lds into one shared 48 KB dbuf (24 sections; 3 per wave),
// one barrier per step (16 total). A frags per-lane direct fp32 + in-reg
// pack, register-prefetched one step ahead.
// ---------------------------------------------------------------------------
__global__ __launch_bounds__(512) void qkv_gemm(
    const float* __restrict__ X, const u16* __restrict__ W,
    const float* __restrict__ bias, u16* __restrict__ Out)
{
    __shared__ short8 Bs[2][1536];   // [p*64 + lane], p = kk2*12 + nt

    const int tid = threadIdx.x;
    const int lane = tid & 63, wid = tid >> 6;   // wid 0..7
    const int q = lane >> 4, r = lane & 15;
    const long m0 = (long)blockIdx.x * 128;

    // B staging pointers: this wave covers p = wid*3 .. wid*3+2
    const u16* wp[3];
    #pragma unroll
    for (int i = 0; i < 3; ++i) {
        const int p = wid * 3 + i, kk2 = p / 12, nt = p % 12;
        wp[i] = W + (long)(nt * 16 + r) * 1024 + kk2 * 32 + q * 8;
    }

    const float* px = X + (m0 + wid * 16 + r) * 1024 + q * 8;

    f32x4 acc[12] = {};

    // prologue: stage step 0 into buf 0; load step-0 A regs
    #pragma unroll
    for (int i = 0; i < 3; ++i)
        gld16(&Bs[0][(wid * 3 + i) * 64], wp[i]);
    float4 a[4];
    a[0] = *(const float4*)(px);
    a[1] = *(const float4*)(px + 4);
    a[2] = *(const float4*)(px + 32);
    a[3] = *(const float4*)(px + 36);
    __syncthreads();

    for (int k0 = 0; k0 < 1024; k0 += 64) {
        const int buf = (k0 >> 6) & 1;
        float4 an[4] = {};
        if (k0 + 64 < 1024) {
            #pragma unroll
            for (int i = 0; i < 3; ++i)
                gld16(&Bs[buf ^ 1][(wid * 3 + i) * 64], wp[i] + k0 + 64);
            an[0] = *(const float4*)(px + k0 + 64);
            an[1] = *(const float4*)(px + k0 + 68);
            an[2] = *(const float4*)(px + k0 + 96);
            an[3] = *(const float4*)(px + k0 + 100);
        }
        #pragma unroll
        for (int kk2 = 0; kk2 < 2; ++kk2) {
            union { short8 s; unsigned u[4]; } af;
            af.u[0] = pack_bf2(a[kk2 * 2].x, a[kk2 * 2].y);
            af.u[1] = pack_bf2(a[kk2 * 2].z, a[kk2 * 2].w);
            af.u[2] = pack_bf2(a[kk2 * 2 + 1].x, a[kk2 * 2 + 1].y);
            af.u[3] = pack_bf2(a[kk2 * 2 + 1].z, a[kk2 * 2 + 1].w);
            #pragma unroll
            for (int nt = 0; nt < 12; ++nt)
                acc[nt] = __builtin_amdgcn_mfma_f32_16x16x32_bf16(
                    af.s, Bs[buf][(kk2 * 12 + nt) * 64 + lane], acc[nt], 0, 0, 0);
        }
        __syncthreads();
        #pragma unroll
        for (int i = 0; i < 4; ++i) a[i] = an[i];
    }

    #pragma unroll
    for (int nt = 0; nt < 12; ++nt) {
        const int col = nt * 16 + r;
        const float badd = bias[col];
        #pragma unroll
        for (int e = 0; e < 4; ++e) {
            const long row = m0 + wid * 16 + q * 4 + e;
            Out[row * 192 + col] = f2bf(acc[nt][e] + badd);
        }
    }
}

// ---------------------------------------------------------------------------
// V transpose: Vt[bh*64 + d][i] <- qkv[b*8192 + i*16 + h][128 + d]
// ---------------------------------------------------------------------------
__global__ __launch_bounds__(256) void vtrans(
    const u16* __restrict__ qkv, u16* __restrict__ Vt)
{
    __shared__ u16 T[64][68];
    const int bh = blockIdx.x, b = bh >> 4, h = bh & 15;
    const int i0 = blockIdx.y * 64;
    const int tid = threadIdx.x;

    #pragma unroll
    for (int it = 0; it < 2; ++it) {
        const int c = tid + 256 * it;
        const int il = c >> 3, d8 = (c & 7) * 8;
        short8 v = *(const short8*)(qkv +
            ((long)b * 8192 + (long)(i0 + il) * 16 + h) * 192 + 128 + d8);
        #pragma unroll
        for (int j = 0; j < 8; ++j) T[d8 + j][il] = (u16)v[j];
    }
    __syncthreads();
    #pragma unroll
    for (int it = 0; it < 2; ++it) {
        const int c = tid + 256 * it;
        const int dl = c >> 3, i8 = (c & 7) * 8;
        short8 o;
        #pragma unroll
        for (int j = 0; j < 8; ++j) o[j] = (short)T[dl][i8 + j];
        *(short8*)(Vt + ((long)bh * 64 + dl) * 512 + i0 + i8) = o;
    }
}

// ---------------------------------------------------------------------------
// Fused flash attention, S^T formulation (unchanged from R6).
// ---------------------------------------------------------------------------
__global__ __launch_bounds__(256) void attn_flash(
    const u16* __restrict__ qkv, const u16* __restrict__ Vt,
    u16* __restrict__ ctx)
{
    __shared__ short8 Ks[2][512];      // [f*256 + ct*64 + q*16 + r]
    __shared__ short8 Vs[2][512];      // [f*256 + nt*64 + q*16 + r]
    __shared__ u16 Plds[4][16 * 72];   // wave-private P[query][key]

    const int tid = threadIdx.x, lane = tid & 63, wid = tid >> 6;
    const int q = lane >> 4, r = lane & 15;
    const int qt = blockIdx.x;         // 0..7
    const int bh = blockIdx.y;         // 0..63
    const int b = bh >> 4, h = bh & 15;
    const long qrowbase = (long)b * 8192 + h;

    // Q B-fragments: lane(q,r) needs Q[query=r][d=q*8+j] (2 d-halves)
    short8 Qf0, Qf1;
    {
        const int i = qt * 64 + wid * 16 + r;
        const u16* p = qkv + (qrowbase + (long)i * 16) * 192 + q * 8;
        Qf0 = *(const short8*)(p);
        Qf1 = *(const short8*)(p + 32);
    }

    const u16* kbase = qkv + (qrowbase + (long)(wid * 16 + r) * 16) * 192
                           + 64 + q * 8;                 // + key*3072 + f*32
    const u16* vbase = Vt + ((long)bh * 64 + wid * 16 + r) * 512 + q * 8;

    gld16(&Ks[0][wid * 64],       kbase);
    gld16(&Ks[0][256 + wid * 64], kbase + 32);
    gld16(&Vs[0][wid * 64],       vbase);
    gld16(&Vs[0][256 + wid * 64], vbase + 32);
    __syncthreads();

    f32x4 O[4] = {};
    float mrun = -1e30f, lrun = 0.f;   // per-lane scalars (query = r)
    u16* Pw = &Plds[wid][0];

    for (int c = 0; c < 8; ++c) {
        const int j0 = c * 64, buf = c & 1;
        if (c < 7) {
            const u16* kp = kbase + (long)(j0 + 64) * 3072;
            const u16* vp = vbase + j0 + 64;
            gld16(&Ks[buf ^ 1][wid * 64],       kp);
            gld16(&Ks[buf ^ 1][256 + wid * 64], kp + 32);
            gld16(&Vs[buf ^ 1][wid * 64],       vp);
            gld16(&Vs[buf ^ 1][256 + wid * 64], vp + 32);
        }
        // ---- S^T chunk: lane holds S^T[key=ct*16+q*4+e][query r] ----
        f32x4 S[4];
        #pragma unroll
        for (int ct = 0; ct < 4; ++ct) {
            f32x4 s = {};
            s = __builtin_amdgcn_mfma_f32_16x16x32_bf16(
                Ks[buf][ct * 64 + lane], Qf0, s, 0, 0, 0);
            s = __builtin_amdgcn_mfma_f32_16x16x32_bf16(
                Ks[buf][256 + ct * 64 + lane], Qf1, s, 0, 0, 0);
            S[ct] = s;
        }
        // ---- online softmax (per query r): in-lane 16 + 2 shuffles ----
        float mc = -1e30f;
        #pragma unroll
        for (int ct = 0; ct < 4; ++ct)
            mc = fmaxf(mc, fmaxf(fmaxf(S[ct][0], S[ct][1]),
                                 fmaxf(S[ct][2], S[ct][3])));
        mc = fmaxf(mc, __shfl_xor(mc, 16, 64));
        mc = fmaxf(mc, __shfl_xor(mc, 32, 64));
        const float mnew = fmaxf(mrun, mc);
        const float alpha = __expf(mrun - mnew);
        mrun = mnew;
        float se = 0.f;
        #pragma unroll
        for (int ct = 0; ct < 4; ++ct)
            #pragma unroll
            for (int e = 0; e < 4; ++e) {
                const float pv = __expf(S[ct][e] - mnew);
                S[ct][e] = pv; se += pv;
            }
        se += __shfl_xor(se, 16, 64);
        se += __shfl_xor(se, 32, 64);
        lrun = lrun * alpha + se;
        #pragma unroll
        for (int nt = 0; nt < 4; ++nt)
            #pragma unroll
            for (int e = 0; e < 4; ++e) O[nt][e] *= alpha;
        // ---- P^T -> LDS as P[query][key], packed b64 writes ----
        #pragma unroll
        for (int ct = 0; ct < 4; ++ct) {
            uint2 d;
            d.x = pack_bf2(S[ct][0], S[ct][1]);
            d.y = pack_bf2(S[ct][2], S[ct][3]);
            *(uint2*)(Pw + r * 72 + ct * 16 + q * 4) = d;
        }
        short8 Pf0 = *(const short8*)(Pw + r * 72 + q * 8);
        short8 Pf1 = *(const short8*)(Pw + r * 72 + 32 + q * 8);
        // ---- O^T += MFMA(A=V^T, B=P) ----
        #pragma unroll
        for (int nt = 0; nt < 4; ++nt) {
            O[nt] = __builtin_amdgcn_mfma_f32_16x16x32_bf16(
                Vs[buf][nt * 64 + lane], Pf0, O[nt], 0, 0, 0);
            O[nt] = __builtin_amdgcn_mfma_f32_16x16x32_bf16(
                Vs[buf][256 + nt * 64 + lane], Pf1, O[nt], 0, 0, 0);
        }
        __syncthreads();
    }

    // ---- epilogue: normalize, write ctx[b*512+i][h*64+d], 8B stores ----
    const float inv = 1.0f / lrun;
    const long i = qt * 64 + wid * 16 + r;
    u16* po = ctx + ((long)b * 512 + i) * 1024 + h * 64;
    #pragma unroll
    for (int nt = 0; nt < 4; ++nt) {
        uint2 d;
        d.x = pack_bf2(O[nt][0] * inv, O[nt][1] * inv);
        d.y = pack_bf2(O[nt][2] * inv, O[nt][3] * inv);
        *(uint2*)(po + nt * 16 + q * 4) = d;
    }
}

// ---------------------------------------------------------------------------
// Output projection (unchanged from R6): out[2048][1024] fp32 = ctx @ Wob^T
// + bo. 64x64 tile, BK=64, both operands via global_load_lds, dbuf, one
// barrier per step. Waves 2x2; wave = 32m x 32n.
// ---------------------------------------------------------------------------
__global__ __launch_bounds__(256) void gemm_o(
    const u16* __restrict__ A, const u16* __restrict__ B,
    const float* __restrict__ bias, float* __restrict__ C)
{
    __shared__ short8 As[2][512];   // [f*256 + mt*64 + q*16 + r]
    __shared__ short8 Bs[2][512];

    const int tid = threadIdx.x;
    const int lane = tid & 63, wid = tid >> 6;
    const int q = lane >> 4, r = lane & 15;
    const long m0 = (long)blockIdx.x * 64, n0 = (long)blockIdx.y * 64;
    const int wm = wid >> 1, wn = wid & 1;

    const u16* ap[2];
    const u16* bp[2];
    #pragma unroll
    for (int i = 0; i < 2; ++i) {
        const int t = wid * 2 + i, f = t >> 2, mt = t & 3;
        ap[i] = A + (m0 + mt * 16 + r) * 1024 + f * 32 + q * 8;
        bp[i] = B + (n0 + mt * 16 + r) * 1024 + f * 32 + q * 8;
    }

    #pragma unroll
    for (int i = 0; i < 2; ++i) {
        gld16(&As[0][(wid * 2 + i) * 64], ap[i]);
        gld16(&Bs[0][(wid * 2 + i) * 64], bp[i]);
    }
    __syncthreads();

    f32x4 acc[2][2] = {};

    for (int k0 = 0; k0 < 1024; k0 += 64) {
        const int buf = (k0 >> 6) & 1;
        if (k0 + 64 < 1024) {
            #pragma unroll
            for (int i = 0; i < 2; ++i) {
                gld16(&As[buf ^ 1][(wid * 2 + i) * 64], ap[i] + k0 + 64);
                gld16(&Bs[buf ^ 1][(wid * 2 + i) * 64], bp[i] + k0 + 64);
            }
        }
        #pragma unroll
        for (int f = 0; f < 2; ++f) {
            short8 af0 = As[buf][f * 256 + (wm * 2 + 0) * 64 + lane];
            short8 af1 = As[buf][f * 256 + (wm * 2 + 1) * 64 + lane];
            short8 bf0 = Bs[buf][f * 256 + (wn * 2 + 0) * 64 + lane];
            short8 bf1 = Bs[buf][f * 256 + (wn * 2 + 1) * 64 + lane];
            acc[0][0] = __builtin_amdgcn_mfma_f32_16x16x32_bf16(af0, bf0, acc[0][0], 0, 0, 0);
            acc[0][1] = __builtin_amdgcn_mfma_f32_16x16x32_bf16(af0, bf1, acc[0][1], 0, 0, 0);
            acc[1][0] = __builtin_amdgcn_mfma_f32_16x16x32_bf16(af1, bf0, acc[1][0], 0, 0, 0);
            acc[1][1] = __builtin_amdgcn_mfma_f32_16x16x32_bf16(af1, bf1, acc[1][1], 0, 0, 0);
        }
        __syncthreads();
    }

    #pragma unroll
    for (int i = 0; i < 2; ++i)
        #pragma unroll
        for (int j = 0; j < 2; ++j) {
            const long col = n0 + (wn * 2 + j) * 16 + r;
            const float badd = bias[col];
            #pragma unroll
            for (int e = 0; e < 4; ++e) {
                const long row = m0 + (wm * 2 + i) * 16 + q * 4 + e;
                C[row * 1024 + col] = acc[i][j][e] + badd;
            }
        }
}

// ---------------------------------------------------------------------------
extern "C" void kernel_launch(void* const* d_in, const int* in_sizes, int n_in,
                              void* d_out, int out_size, void* d_ws, size_t ws_size,
                              hipStream_t stream)
{
    const float* x  = (const float*)d_in[0];
    const float* Wq = (const float*)d_in[1];
    const float* bq = (const float*)d_in[2];
    const float* Wk = (const float*)d_in[3];
    const float* bk = (const float*)d_in[4];
    const float* Wv = (const float*)d_in[5];
    const float* bv = (const float*)d_in[6];
    const float* Wo = (const float*)d_in[7];
    const float* bo = (const float*)d_in[8];
    float* out = (float*)d_out;
    char* ws = (char*)d_ws;

    u16*   qkv  = (u16*)(ws);                   // 32768*192*2   = 12,582,912
    u16*   Vt   = (u16*)(ws + 12582912);        // 64*64*512*2   =  4,194,304
    u16*   Wqkv = (u16*)(ws + 16777216);        // 192*1024*2    =    393,216
    u16*   Wob  = (u16*)(ws + 17170432);        // 1024*1024*2   =  2,097,152
    float* qkvb = (float*)(ws + 19267584);      // 192*4
    u16*   ctx  = (u16*)(ws + 19268352);        // 2048*1024*2   =  4,194,304

    convw<<<4096, 256, 0, stream>>>(Wq, bq, Wk, bk, Wv, bv, Wo, Wqkv, qkvb, Wob);
    qkv_gemm<<<256, 512, 0, stream>>>(x, Wqkv, qkvb, qkv);
    vtrans<<<dim3(64, 8), 256, 0, stream>>>(qkv, Vt);
    attn_flash<<<dim3(8, 64), 256, 0, stream>>>(qkv, Vt, ctx);
    gemm_o<<<dim3(32, 16), 256, 0, stream>>>(ctx, Wob, bo, out);
}